// Round 3
// baseline (265.592 us; speedup 1.0000x reference)
//
#include <hip/hip_runtime.h>
#include <math.h>

#define N_BATCH 8
#define IN_CH   256
#define OUT_CH  256
#define T_LEN   2048
#define DKS     33
#define PAD     16
#define KC      16

#define MT 64        // o per block
#define TT 128       // t per block (and per wave)
#define XS_ROWS 160  // TT + 2*PAD
#define XS_STRIDE 40 // ushort elems; 80B rows (16B-aligned)

typedef __attribute__((ext_vector_type(8))) short bf16x8;
typedef __attribute__((ext_vector_type(4))) float f32x4;

__device__ __forceinline__ unsigned short f2bf(float f) {
    unsigned u = __builtin_bit_cast(unsigned, f);
    unsigned r = (u + 0x7FFFu + ((u >> 16) & 1u)) >> 16;   // RNE
    return (unsigned short)r;
}

// ---------------------------------------------------------------------------
// Kernel 1 (v3): dense conv kernel in bf16, fragment-ready global layout
//   elem(o,i,d) at ((g*8+c)*33+d)*2048 + ai*512 + (q*16+m)*8 + j
//   g=o>>6, ai=(o>>4)&3, m=o&15, c=i>>5, q=(i&31)>>3, j=i&7.
// One block per (g,c,ai): 64 lanes, lane l=q*16+m handles 8 j's.
// LDS transpose buffer -> every global store is a full-line dwordx4
// (lane l writes 16B at base + d*4096 + l*16 : perfectly coalesced).
// Reference semantics preserved: frac from out-channel 0; second tap
// dropped when p1+1 == 33.
// ---------------------------------------------------------------------------
__global__ __launch_bounds__(64) void build_kern(
    const float* __restrict__ weight,
    const float* __restrict__ P,
    unsigned short* __restrict__ kern_f)
{
    __shared__ unsigned short Ls[DKS * 512];   // 33.8 KB

    const int bid = blockIdx.x;        // 128 blocks
    const int ai = bid & 3;
    const int c  = (bid >> 2) & 7;
    const int g  = bid >> 5;
    const int l  = threadIdx.x;
    const int q  = l >> 4, m = l & 15;
    const int o  = g * 64 + ai * 16 + m;

    for (int j = 0; j < 8; ++j) {
        int i = c * 32 + q * 8 + j;
        float a[DKS];
#pragma unroll
        for (int d = 0; d < DKS; ++d) a[d] = 0.0f;

        const float* Po = P      + (size_t)(o * IN_CH + i) * KC;
        const float* P0 = P      + (size_t)i * KC;          // out-channel 0
        const float* Wo = weight + (size_t)(o * IN_CH + i) * KC;
#pragma unroll
        for (int k = 0; k < KC; ++k) {
            float pp   = Po[k] + (float)(DKS / 2);
            float p0   = P0[k] + (float)(DKS / 2);
            float frac = p0 - floorf(p0);
            int   p1   = (int)floorf(pp);
            float w    = Wo[k];
            a[p1] += w * (1.0f - frac);
            if (p1 + 1 < DKS) a[p1 + 1] += w * frac;
        }
#pragma unroll
        for (int d = 0; d < DKS; ++d)
            Ls[d * 512 + l * 8 + j] = f2bf(a[d]);
    }
    __syncthreads();

    const size_t base = ((size_t)(g * 8 + c) * DKS) * 2048 + (size_t)ai * 512;
#pragma unroll
    for (int d = 0; d < DKS; ++d)
        *(bf16x8*)(kern_f + base + (size_t)d * 2048 + l * 8) =
            *(const bf16x8*)(Ls + d * 512 + l * 8);
}

// ---------------------------------------------------------------------------
// Kernel 2: implicit-GEMM conv, MFMA 16x16x32 bf16.
// 512 blocks (2/CU), 256 thr = 4 waves. Block tile 64o x 128t.
// Each WAVE computes the full 64o x 128t tile over 2 of the 8 i-chunks
// (intra-block K-split), acc = 4x8 frags = 128 VGPRs.
// Per d-step per wave: 4 A-frags (L1 global, fragment-layout) feed 32 MFMAs
// -> 4x the A-reuse of round 2 (which was A-path-bound at 23% MfmaUtil).
// Final: LDS tree-reduction across the 4 waves, distributed epilogue.
// ---------------------------------------------------------------------------
__global__ __launch_bounds__(256, 2) void dcls_conv(
    const float* __restrict__ x,
    const unsigned short* __restrict__ kern_f,
    const float* __restrict__ bias,
    float* __restrict__ out)
{
    __shared__ unsigned short Xs[4 * XS_ROWS * XS_STRIDE];   // 51.2 KB

    // XCD-aware swizzle: id&7 ~ XCD slot; same o-group (kern slice 1.08MB)
    // stays on one XCD's L2.
    const int id = blockIdx.x;                 // 0..511
    const int g  = (id & 7) >> 1;              // o-group 0..3
    const int tb = ((id >> 3) << 1) | (id & 1);// 0..127
    const int ttile = tb & 15;
    const int batch = tb >> 4;
    const int t0 = ttile * TT;
    const int o0 = g * MT;

    const int tid  = threadIdx.x;
    const int w    = tid >> 6;
    const int l    = tid & 63;
    const int quad = l >> 4;
    const int lm   = l & 15;

    f32x4 acc[4][8];
#pragma unroll
    for (int a = 0; a < 4; ++a)
#pragma unroll
        for (int b = 0; b < 8; ++b) acc[a][b] = (f32x4){0.f, 0.f, 0.f, 0.f};

    for (int p = 0; p < 2; ++p) {
        __syncthreads();
        // ---- stage chunks p*4+s (s=0..3) into slots s: 4 x 160t x 32i ----
#pragma unroll
        for (int it = 0; it < 40; ++it) {
            int idx = tid + it * 256;          // 0..10239
            int s   = idx / 2560;
            int r   = idx - s * 2560;
            int ip  = r / XS_ROWS;             // i-pair 0..15
            int t   = r - ip * XS_ROWS;        // 0..159
            int gg  = t0 - PAD + t;
            int i   = (p * 4 + s) * 32 + ip * 2;
            float v0 = 0.f, v1 = 0.f;
            if ((unsigned)gg < (unsigned)T_LEN) {
                const float* xb = x + ((size_t)(batch * IN_CH + i)) * T_LEN + gg;
                v0 = xb[0];
                v1 = xb[T_LEN];
            }
            unsigned pk = (unsigned)f2bf(v0) | ((unsigned)f2bf(v1) << 16);
            *(unsigned*)(&Xs[(s * XS_ROWS + t) * XS_STRIDE + ip * 2]) = pk;
        }
        __syncthreads();

        // ---- wave w consumes chunk c = p*4 + w from slot w ----
        const int c = p * 4 + w;
        const unsigned short* kf = kern_f
            + ((size_t)(g * 8 + c) * DKS) * 2048 + (size_t)l * 8;
        const unsigned short* xsb = &Xs[(w * XS_ROWS) * XS_STRIDE + quad * 8];

        bf16x8 af[4];
#pragma unroll
        for (int a = 0; a < 4; ++a)
            af[a] = *(const bf16x8*)(kf + a * 512);

        for (int d = 0; d < DKS; ++d) {
            bf16x8 cur[4];
#pragma unroll
            for (int a = 0; a < 4; ++a) cur[a] = af[a];
            if (d + 1 < DKS) {
#pragma unroll
                for (int a = 0; a < 4; ++a)
                    af[a] = *(const bf16x8*)(kf + (size_t)(d + 1) * 2048 + a * 512);
            }
            bf16x8 bfr[8];
#pragma unroll
            for (int b = 0; b < 8; ++b)
                bfr[b] = *(const bf16x8*)(xsb + (b * 16 + lm + d) * XS_STRIDE);
#pragma unroll
            for (int a = 0; a < 4; ++a)
#pragma unroll
                for (int b = 0; b < 8; ++b)
                    acc[a][b] = __builtin_amdgcn_mfma_f32_16x16x32_bf16(
                        cur[a], bfr[b], acc[a][b], 0, 0, 0);
        }
    }

    // ---- cross-wave reduction (LDS tree, halves of 16 frags = 16KB) ----
    f32x4* red4 = (f32x4*)Xs;    // capacity 3200 f32x4; we use <= 2048
    __syncthreads();
#pragma unroll
    for (int h = 0; h < 2; ++h) {
        if (w & 1) {                       // waves 1,3 publish half h
            int base = (w == 1) ? 0 : 1024;
#pragma unroll
            for (int f = 0; f < 16; ++f) {
                int fr = h * 16 + f;
                red4[base + f * 64 + l] = acc[fr >> 3][fr & 7];
            }
        }
        __syncthreads();
        if (!(w & 1)) {                    // waves 0,2 absorb
            int base = (w == 0) ? 0 : 1024;
#pragma unroll
            for (int f = 0; f < 16; ++f) {
                int fr = h * 16 + f;
                acc[fr >> 3][fr & 7] += red4[base + f * 64 + l];
            }
        }
        __syncthreads();
    }
    // exchange: w0 takes frags 0..15, w2 takes frags 16..31
    if (w == 0) {
#pragma unroll
        for (int f = 0; f < 16; ++f)
            red4[1024 + f * 64 + l] = acc[2 + (f >> 3)][f & 7];   // frags 16..31
    } else if (w == 2) {
#pragma unroll
        for (int f = 0; f < 16; ++f)
            red4[f * 64 + l] = acc[f >> 3][f & 7];                // frags 0..15
    }
    __syncthreads();

    // ---- distributed epilogue: w0 stores frags 0..15, w2 stores 16..31 ----
    if (w == 0 || w == 2) {
        int base = (w == 0) ? 0 : 1024;
        int fro  = (w == 0) ? 0 : 16;
#pragma unroll
        for (int f = 0; f < 16; ++f) {
            int fr = fro + f;
            int a = fr >> 3, b = fr & 7;
            f32x4 v = acc[a][b] + red4[base + f * 64 + l];
#pragma unroll
            for (int r = 0; r < 4; ++r) {
                int o = o0 + a * 16 + quad * 4 + r;
                out[((size_t)(batch * OUT_CH + o)) * T_LEN + t0 + b * 16 + lm]
                    = v[r] + bias[o];
            }
        }
    }
}

extern "C" void kernel_launch(void* const* d_in, const int* in_sizes, int n_in,
                              void* d_out, int out_size, void* d_ws, size_t ws_size,
                              hipStream_t stream) {
    const float* x      = (const float*)d_in[0];
    const float* weight = (const float*)d_in[1];
    const float* P      = (const float*)d_in[2];
    const float* bias   = (const float*)d_in[3];
    float*       out    = (float*)d_out;
    unsigned short* kern_f = (unsigned short*)d_ws;   // 4.33 MB

    hipLaunchKernelGGL(build_kern, dim3(128), dim3(64), 0, stream,
                       weight, P, kern_f);

    hipLaunchKernelGGL(dcls_conv, dim3(512), dim3(256), 0, stream,
                       x, kern_f, bias, out);
}